// Round 5
// baseline (619.388 us; speedup 1.0000x reference)
//
#include <hip/hip_runtime.h>
#include <hip/hip_bf16.h>

#define M_NODES 100000
#define N_EDGES 1600000
#define K_IN 512
#define N_OUT 256

typedef short bf16x8 __attribute__((ext_vector_type(8)));
typedef float f32x4 __attribute__((ext_vector_type(4)));

__device__ inline unsigned short f2bf_u(float f) {
  union { float f; unsigned u; } x; x.f = f;
  unsigned r = x.u + 0x7FFFu + ((x.u >> 16) & 1u);
  return (unsigned short)(r >> 16);
}
__device__ inline float bfu2f(unsigned short h) {
  union { unsigned u; float f; } x; x.u = ((unsigned)h) << 16;
  return x.f;
}
// tanh(x) = sign(x) * (1-z)/(1+z), z = exp(-2|x|). ~7 VALU + 1 trans.
__device__ inline float fast_tanh(float x) {
  float ax = __builtin_fabsf(x);
  float z = __expf(-2.0f * ax);
  float t = (1.0f - z) * __builtin_amdgcn_rcpf(1.0f + z);
  return __builtin_copysignf(t, x);
}
// pack 8 f32 -> bf16x8 via v_cvt_pk_bf16_f32 (dst.lo = src0, RTNE)
__device__ inline bf16x8 cvt8(float4 lo, float4 hi) {
  union { unsigned u[4]; bf16x8 v; } r;
  asm("v_cvt_pk_bf16_f32 %0, %1, %2" : "=v"(r.u[0]) : "v"(lo.x), "v"(lo.y));
  asm("v_cvt_pk_bf16_f32 %0, %1, %2" : "=v"(r.u[1]) : "v"(lo.z), "v"(lo.w));
  asm("v_cvt_pk_bf16_f32 %0, %1, %2" : "=v"(r.u[2]) : "v"(hi.x), "v"(hi.y));
  asm("v_cvt_pk_bf16_f32 %0, %1, %2" : "=v"(r.u[3]) : "v"(hi.z), "v"(hi.w));
  return r.v;
}

// weight [512][256] f32 -> fragment-major bf16:
// wt[((ks*16+nt)*64 + lane)*8 + j] = bf16(w[ks*32+quad*8+j][nt*16+l16])
// so a wave's B fragment (ks,nt) is 1KB CONTIGUOUS: base + lane*16B.
__global__ void prep_w_kernel(const float* __restrict__ w, short* __restrict__ wt) {
  int frag = blockIdx.x * 256 + threadIdx.x;   // 16384 frags (64 blocks)
  int lane = frag & 63;
  int fi = frag >> 6;                          // ks*16 + nt
  int ks = fi >> 4, nt = fi & 15;
  int quad = lane >> 4, l16 = lane & 15;
  int n = nt * 16 + l16;
  int k0 = ks * 32 + quad * 8;
  #pragma unroll
  for (int j = 0; j < 8; ++j)
    wt[(size_t)frag * 8 + j] = (short)f2bf_u(w[(size_t)(k0 + j) * N_OUT + n]);
}

// row_ptr[r] = lower_bound(row, r) over sorted row[] (COO -> CSR)
__global__ void build_rp_kernel(const int* __restrict__ row, int* __restrict__ rp) {
  int r = blockIdx.x * 256 + threadIdx.x;
  if (r > M_NODES) return;
  int lo = 0, hi = N_EDGES;
  while (lo < hi) {
    int mid = (lo + hi) >> 1;
    if (row[mid] < r) lo = mid + 1; else hi = mid;
  }
  rp[r] = lo;
}

// H = bf16(tanh(A @ W)). Barrier-free, LDS-free, 1 wave per block.
// Wave owns 32 rows x 256 cols (acc 128 f32). 3125 blocks x 32 = 100000
// exactly (no clamps). B from fragment-major Wt (L1/L2-resident, zero addr
// VALU). A from HBM with a 2-kstep register burst.
// NOTE: no min-waves hint in __launch_bounds__ -- the kernel needs ~240
// VGPRs live (acc 128 + B 64 + A 32 + addr); round 4's (64,2) hint made
// the compiler cap at 128 and spill ~100 regs to scratch (FETCH +8MB,
// WRITE +16MB of pure spill traffic). ~240 regs still co-residents
// 2 waves/SIMD (512/240), which this latency-bound structure needs.
// vmcnt ORDER DISCIPLINE (in-order retirement!): per kstep-pair the VMEM
// queue is [bP(odd) bQ(odd) | aA' aB' | bP(next-even) bQ(next-even)] --
// every B-wait has no unretired older A in front of it; the HBM latency
// is paid ONCE per pair at the aA' conv. sched_barrier(0) brackets the
// A-burst so the scheduler cannot hoist/sink loads across it.
__global__ __launch_bounds__(64) void gemm_tanh_kernel(
    const float* __restrict__ A, const short* __restrict__ WtF,
    unsigned short* __restrict__ H) {
  const int lane = threadIdx.x;
  const int quad = lane >> 4, l16 = lane & 15;
  const int R0 = blockIdx.x * 32;

  f32x4 acc0[16], acc1[16];   // m=0 rows R0..R0+15 ; m=1 rows R0+16..R0+31
  #pragma unroll
  for (int i = 0; i < 16; ++i) {
    acc0[i] = (f32x4){0.f, 0.f, 0.f, 0.f};
    acc1[i] = (f32x4){0.f, 0.f, 0.f, 0.f};
  }

  const float* Ab0 = A + (size_t)(R0 + l16) * K_IN + quad * 8;
  const float* Ab1 = Ab0 + (size_t)16 * K_IN;
  const short* Bb = WtF + lane * 8;   // + fi*512 shorts per fragment

  float4 aA[4], aB[4];   // A for even/odd kstep of current pair
  bf16x8 bP[8], bQ[8];   // B halves (nt 0..7 / 8..15) of current kstep

  // ---- prologue. queue: [aA aB bP(0) bQ(0)]
  aA[0] = *(const float4*)(Ab0);      aA[1] = *(const float4*)(Ab0 + 4);
  aA[2] = *(const float4*)(Ab1);      aA[3] = *(const float4*)(Ab1 + 4);
  aB[0] = *(const float4*)(Ab0 + 32); aB[1] = *(const float4*)(Ab0 + 36);
  aB[2] = *(const float4*)(Ab1 + 32); aB[3] = *(const float4*)(Ab1 + 36);
  #pragma unroll
  for (int nt = 0; nt < 8; ++nt)
    bP[nt] = *(const bf16x8*)(Bb + (size_t)nt * 512);
  #pragma unroll
  for (int nt = 0; nt < 8; ++nt)
    bQ[nt] = *(const bf16x8*)(Bb + (size_t)(8 + nt) * 512);

  #pragma unroll
  for (int p = 0; p < 8; ++p) {
    const int ks1 = 2 * p + 1;
    // -- even kstep: conv (waits aA = once-per-pair HBM stall)
    bf16x8 af0 = cvt8(aA[0], aA[1]);
    bf16x8 af1 = cvt8(aA[2], aA[3]);
    #pragma unroll
    for (int nt = 0; nt < 8; ++nt) {
      acc0[nt] = __builtin_amdgcn_mfma_f32_16x16x32_bf16(af0, bP[nt], acc0[nt], 0, 0, 0);
      acc1[nt] = __builtin_amdgcn_mfma_f32_16x16x32_bf16(af1, bP[nt], acc1[nt], 0, 0, 0);
    }
    #pragma unroll
    for (int nt = 0; nt < 8; ++nt)   // refill bP <- B(ks1, nt 0..7)
      bP[nt] = *(const bf16x8*)(Bb + (size_t)(ks1 * 16 + nt) * 512);
    #pragma unroll
    for (int nt = 0; nt < 8; ++nt) {
      acc0[8 + nt] = __builtin_amdgcn_mfma_f32_16x16x32_bf16(af0, bQ[nt], acc0[8 + nt], 0, 0, 0);
      acc1[8 + nt] = __builtin_amdgcn_mfma_f32_16x16x32_bf16(af1, bQ[nt], acc1[8 + nt], 0, 0, 0);
    }
    #pragma unroll
    for (int nt = 0; nt < 8; ++nt)   // refill bQ <- B(ks1, nt 8..15)
      bQ[nt] = *(const bf16x8*)(Bb + (size_t)(ks1 * 16 + 8 + nt) * 512);
    // -- odd kstep conv (aB arrived together with aA)
    bf16x8 ag0 = cvt8(aB[0], aB[1]);
    bf16x8 ag1 = cvt8(aB[2], aB[3]);
    // -- A burst for next pair (AFTER this pair's B, BEFORE next-even B)
    if (p < 7) {
      __builtin_amdgcn_sched_barrier(0);
      const float* pa0 = Ab0 + (2 * p + 2) * 32;
      const float* pa1 = Ab1 + (2 * p + 2) * 32;
      aA[0] = *(const float4*)(pa0);      aA[1] = *(const float4*)(pa0 + 4);
      aA[2] = *(const float4*)(pa1);      aA[3] = *(const float4*)(pa1 + 4);
      aB[0] = *(const float4*)(pa0 + 32); aB[1] = *(const float4*)(pa0 + 36);
      aB[2] = *(const float4*)(pa1 + 32); aB[3] = *(const float4*)(pa1 + 36);
      __builtin_amdgcn_sched_barrier(0);
    }
    // -- odd kstep MFMAs
    #pragma unroll
    for (int nt = 0; nt < 8; ++nt) {
      acc0[nt] = __builtin_amdgcn_mfma_f32_16x16x32_bf16(ag0, bP[nt], acc0[nt], 0, 0, 0);
      acc1[nt] = __builtin_amdgcn_mfma_f32_16x16x32_bf16(ag1, bP[nt], acc1[nt], 0, 0, 0);
    }
    #pragma unroll
    for (int nt = 0; nt < 8; ++nt) {
      acc0[8 + nt] = __builtin_amdgcn_mfma_f32_16x16x32_bf16(ag0, bQ[nt], acc0[8 + nt], 0, 0, 0);
      acc1[8 + nt] = __builtin_amdgcn_mfma_f32_16x16x32_bf16(ag1, bQ[nt], acc1[8 + nt], 0, 0, 0);
    }
    // -- refill bP/bQ for next even kstep (issued AFTER the A burst)
    if (p < 7) {
      #pragma unroll
      for (int nt = 0; nt < 8; ++nt)
        bP[nt] = *(const bf16x8*)(Bb + (size_t)((ks1 + 1) * 16 + nt) * 512);
      #pragma unroll
      for (int nt = 0; nt < 8; ++nt)
        bQ[nt] = *(const bf16x8*)(Bb + (size_t)((ks1 + 1) * 16 + 8 + nt) * 512);
    }
  }

  // ---- epilogue: row = R0 + m*16 + quad*4 + rr, col = nt*16 + l16
  #pragma unroll
  for (int nt = 0; nt < 16; ++nt) {
    #pragma unroll
    for (int rr = 0; rr < 4; ++rr) {
      int r0 = R0 + quad * 4 + rr;
      H[(size_t)r0 * N_OUT + nt * 16 + l16] = f2bf_u(fast_tanh(acc0[nt][rr]));
      H[(size_t)(r0 + 16) * N_OUT + nt * 16 + l16] = f2bf_u(fast_tanh(acc1[nt][rr]));
    }
  }
}

// y[i,:] = sum_e vals[e]*x[col[e],:], x bf16 [M,256]. One wave/row; lane holds
// 4 features (8B/edge/lane -> full 512B row per edge, coalesced).
// Edge metadata (col/vals) loaded once per 64-edge chunk as a per-lane
// vector load, broadcast via __shfl. Gathers issued 16-DEEP (round 4 was
// 8-deep at VGPR=28 / occupancy 69% / nothing pegged -> latency-bound;
// doubling MLP is free in registers).
__global__ __launch_bounds__(256) void spmm_bf_bf(
    const int* __restrict__ rp, const int* __restrict__ colv,
    const float* __restrict__ vals, const unsigned short* __restrict__ x,
    unsigned short* __restrict__ y) {
  int w = (blockIdx.x * 256 + threadIdx.x) >> 6;
  int lane = threadIdx.x & 63;
  int i = __builtin_amdgcn_readfirstlane(w);
  int s = rp[i], e = rp[i + 1];
  float a0 = 0.f, a1 = 0.f, a2 = 0.f, a3 = 0.f;
  const unsigned short* xl = x + lane * 4;
  for (int base = s; base < e; base += 64) {
    int nn = min(e - base, 64);
    int tl = min(base + lane, e - 1);          // clamped: lanes >= nn unused
    int c_l = colv[tl];
    float v_l = vals[tl];
    int tt = 0;
    for (; tt + 16 <= nn; tt += 16) {
      ushort4 xv[16]; float vv[16];
      #pragma unroll
      for (int j = 0; j < 16; ++j) {
        int c = __shfl(c_l, tt + j);
        vv[j] = __shfl(v_l, tt + j);
        xv[j] = *(const ushort4*)(xl + (size_t)c * N_OUT);
      }
      #pragma unroll
      for (int j = 0; j < 16; ++j) {
        a0 += vv[j] * bfu2f(xv[j].x); a1 += vv[j] * bfu2f(xv[j].y);
        a2 += vv[j] * bfu2f(xv[j].z); a3 += vv[j] * bfu2f(xv[j].w);
      }
    }
    for (; tt + 8 <= nn; tt += 8) {
      ushort4 xv[8]; float vv[8];
      #pragma unroll
      for (int j = 0; j < 8; ++j) {
        int c = __shfl(c_l, tt + j);
        vv[j] = __shfl(v_l, tt + j);
        xv[j] = *(const ushort4*)(xl + (size_t)c * N_OUT);
      }
      #pragma unroll
      for (int j = 0; j < 8; ++j) {
        a0 += vv[j] * bfu2f(xv[j].x); a1 += vv[j] * bfu2f(xv[j].y);
        a2 += vv[j] * bfu2f(xv[j].z); a3 += vv[j] * bfu2f(xv[j].w);
      }
    }
    for (; tt + 4 <= nn; tt += 4) {
      ushort4 xv[4]; float vv[4];
      #pragma unroll
      for (int j = 0; j < 4; ++j) {
        int c = __shfl(c_l, tt + j);
        vv[j] = __shfl(v_l, tt + j);
        xv[j] = *(const ushort4*)(xl + (size_t)c * N_OUT);
      }
      #pragma unroll
      for (int j = 0; j < 4; ++j) {
        a0 += vv[j] * bfu2f(xv[j].x); a1 += vv[j] * bfu2f(xv[j].y);
        a2 += vv[j] * bfu2f(xv[j].z); a3 += vv[j] * bfu2f(xv[j].w);
      }
    }
    for (; tt < nn; ++tt) {
      int c = __shfl(c_l, tt);
      float v = __shfl(v_l, tt);
      ushort4 xv = *(const ushort4*)(xl + (size_t)c * N_OUT);
      a0 += v * bfu2f(xv.x); a1 += v * bfu2f(xv.y);
      a2 += v * bfu2f(xv.z); a3 += v * bfu2f(xv.w);
    }
  }
  ushort4 o;
  o.x = f2bf_u(a0); o.y = f2bf_u(a1); o.z = f2bf_u(a2); o.w = f2bf_u(a3);
  *(ushort4*)(y + (size_t)i * N_OUT + lane * 4) = o;
}

// same but f32 output (final layer writes d_out)
__global__ __launch_bounds__(256) void spmm_bf_f32(
    const int* __restrict__ rp, const int* __restrict__ colv,
    const float* __restrict__ vals, const unsigned short* __restrict__ x,
    float* __restrict__ y) {
  int w = (blockIdx.x * 256 + threadIdx.x) >> 6;
  int lane = threadIdx.x & 63;
  int i = __builtin_amdgcn_readfirstlane(w);
  int s = rp[i], e = rp[i + 1];
  float a0 = 0.f, a1 = 0.f, a2 = 0.f, a3 = 0.f;
  const unsigned short* xl = x + lane * 4;
  for (int base = s; base < e; base += 64) {
    int nn = min(e - base, 64);
    int tl = min(base + lane, e - 1);
    int c_l = colv[tl];
    float v_l = vals[tl];
    int tt = 0;
    for (; tt + 16 <= nn; tt += 16) {
      ushort4 xv[16]; float vv[16];
      #pragma unroll
      for (int j = 0; j < 16; ++j) {
        int c = __shfl(c_l, tt + j);
        vv[j] = __shfl(v_l, tt + j);
        xv[j] = *(const ushort4*)(xl + (size_t)c * N_OUT);
      }
      #pragma unroll
      for (int j = 0; j < 16; ++j) {
        a0 += vv[j] * bfu2f(xv[j].x); a1 += vv[j] * bfu2f(xv[j].y);
        a2 += vv[j] * bfu2f(xv[j].z); a3 += vv[j] * bfu2f(xv[j].w);
      }
    }
    for (; tt + 8 <= nn; tt += 8) {
      ushort4 xv[8]; float vv[8];
      #pragma unroll
      for (int j = 0; j < 8; ++j) {
        int c = __shfl(c_l, tt + j);
        vv[j] = __shfl(v_l, tt + j);
        xv[j] = *(const ushort4*)(xl + (size_t)c * N_OUT);
      }
      #pragma unroll
      for (int j = 0; j < 8; ++j) {
        a0 += vv[j] * bfu2f(xv[j].x); a1 += vv[j] * bfu2f(xv[j].y);
        a2 += vv[j] * bfu2f(xv[j].z); a3 += vv[j] * bfu2f(xv[j].w);
      }
    }
    for (; tt + 4 <= nn; tt += 4) {
      ushort4 xv[4]; float vv[4];
      #pragma unroll
      for (int j = 0; j < 4; ++j) {
        int c = __shfl(c_l, tt + j);
        vv[j] = __shfl(v_l, tt + j);
        xv[j] = *(const ushort4*)(xl + (size_t)c * N_OUT);
      }
      #pragma unroll
      for (int j = 0; j < 4; ++j) {
        a0 += vv[j] * bfu2f(xv[j].x); a1 += vv[j] * bfu2f(xv[j].y);
        a2 += vv[j] * bfu2f(xv[j].z); a3 += vv[j] * bfu2f(xv[j].w);
      }
    }
    for (; tt < nn; ++tt) {
      int c = __shfl(c_l, tt);
      float v = __shfl(v_l, tt);
      ushort4 xv = *(const ushort4*)(xl + (size_t)c * N_OUT);
      a0 += v * bfu2f(xv.x); a1 += v * bfu2f(xv.y);
      a2 += v * bfu2f(xv.z); a3 += v * bfu2f(xv.w);
    }
  }
  float4 o = {a0, a1, a2, a3};
  *(float4*)(y + (size_t)i * N_OUT + lane * 4) = o;
}

extern "C" void kernel_launch(void* const* d_in, const int* in_sizes, int n_in,
                              void* d_out, int out_size, void* d_ws, size_t ws_size,
                              hipStream_t stream) {
  const float* features = (const float*)d_in[0];
  const float* weight   = (const float*)d_in[1];
  const int*   row      = (const int*)d_in[2];
  const int*   col      = (const int*)d_in[3];
  const float* vals     = (const float*)d_in[4];
  float* out = (float*)d_out;

  char* ws = (char*)d_ws;
  const size_t HB = (size_t)M_NODES * N_OUT * 2;   // 51,200,000 bf16 H
  const size_t RPB = 400016;                        // 100001 ints padded
  unsigned short* H  = (unsigned short*)ws;
  unsigned short* y1 = (unsigned short*)(ws + HB);
  int*   rp = (int*)(ws + 2 * HB);
  short* Wt = (short*)(ws + 2 * HB + RPB);
  // total need: 2*51.2MB + 400016 + 262144 = 103,062,160 B (fits)

  prep_w_kernel<<<64, 256, 0, stream>>>(weight, Wt);
  build_rp_kernel<<<(M_NODES + 1 + 255) / 256, 256, 0, stream>>>(row, rp);
  // 1 wave/block, 32 rows/wave, 3125*32 = 100000 exactly
  gemm_tanh_kernel<<<3125, 64, 0, stream>>>(features, Wt, H);
  spmm_bf_bf<<<25000, 256, 0, stream>>>(rp, col, vals, H, y1);
  spmm_bf_f32<<<25000, 256, 0, stream>>>(rp, col, vals, y1, out);
}

// Round 6
// 582.074 us; speedup vs baseline: 1.0641x; 1.0641x over previous
//
#include <hip/hip_runtime.h>
#include <hip/hip_bf16.h>

#define M_NODES 100000
#define N_EDGES 1600000
#define K_IN 512
#define N_OUT 256

typedef short bf16x8 __attribute__((ext_vector_type(8)));
typedef float f32x4 __attribute__((ext_vector_type(4)));

#define GLOBAL_AS __attribute__((address_space(1)))
#define LDS_AS __attribute__((address_space(3)))

__device__ inline unsigned short f2bf_u(float f) {
  union { float f; unsigned u; } x; x.f = f;
  unsigned r = x.u + 0x7FFFu + ((x.u >> 16) & 1u);
  return (unsigned short)(r >> 16);
}
__device__ inline float bfu2f(unsigned short h) {
  union { unsigned u; float f; } x; x.u = ((unsigned)h) << 16;
  return x.f;
}
// tanh(x) = sign(x) * (1-z)/(1+z), z = exp(-2|x|). ~7 VALU + 1 trans.
__device__ inline float fast_tanh(float x) {
  float ax = __builtin_fabsf(x);
  float z = __expf(-2.0f * ax);
  float t = (1.0f - z) * __builtin_amdgcn_rcpf(1.0f + z);
  return __builtin_copysignf(t, x);
}
// pack 8 f32 -> bf16x8 via v_cvt_pk_bf16_f32 (dst.lo = src0, RTNE)
__device__ inline bf16x8 cvt8(f32x4 lo, f32x4 hi) {
  union { unsigned u[4]; bf16x8 v; } r;
  asm("v_cvt_pk_bf16_f32 %0, %1, %2" : "=v"(r.u[0]) : "v"(lo[0]), "v"(lo[1]));
  asm("v_cvt_pk_bf16_f32 %0, %1, %2" : "=v"(r.u[1]) : "v"(lo[2]), "v"(lo[3]));
  asm("v_cvt_pk_bf16_f32 %0, %1, %2" : "=v"(r.u[2]) : "v"(hi[0]), "v"(hi[1]));
  asm("v_cvt_pk_bf16_f32 %0, %1, %2" : "=v"(r.u[3]) : "v"(hi[2]), "v"(hi[3]));
  return r.v;
}

// weight [512][256] f32 -> fragment-major bf16:
// wt[((ks*16+nt)*64 + lane)*8 + j] = bf16(w[ks*32+quad*8+j][nt*16+l16])
// so a wave's B fragment (ks,nt) is 1KB CONTIGUOUS: base + lane*16B, and a
// k-step's 16 fragments are one linear 16KB range (DMA-stageable as a copy).
__global__ void prep_w_kernel(const float* __restrict__ w, short* __restrict__ wt) {
  int frag = blockIdx.x * 256 + threadIdx.x;   // 16384 frags (64 blocks)
  int lane = frag & 63;
  int fi = frag >> 6;                          // ks*16 + nt
  int ks = fi >> 4, nt = fi & 15;
  int quad = lane >> 4, l16 = lane & 15;
  int n = nt * 16 + l16;
  int k0 = ks * 32 + quad * 8;
  #pragma unroll
  for (int j = 0; j < 8; ++j)
    wt[(size_t)frag * 8 + j] = (short)f2bf_u(w[(size_t)(k0 + j) * N_OUT + n]);
}

// row_ptr[r] = lower_bound(row, r) over sorted row[] (COO -> CSR)
__global__ void build_rp_kernel(const int* __restrict__ row, int* __restrict__ rp) {
  int r = blockIdx.x * 256 + threadIdx.x;
  if (r > M_NODES) return;
  int lo = 0, hi = N_EDGES;
  while (lo < hi) {
    int mid = (lo + hi) >> 1;
    if (row[mid] < r) lo = mid + 1; else hi = mid;
  }
  rp[r] = lo;
}

// H = bf16(tanh(A @ W)). A fp32 [M,512], WtF fragment-major bf16.
// m97-style memory-bound pipeline: ALL staging via global_load_lds width-16
// (R3-R5 post-mortem: register prefetch keeps only ~100s of bytes in flight
// per CU -> 1.3 TB/s latency wall; DMA bursts put ~24KB/block in flight).
// BM=64 x BN=256 (A read ONCE), BK=32, 256 thr / 4 waves, wave owns 64 cols,
// acc[4][4] (64 VGPR, no spill). LDS double-buffered 2x(8KB A fp32 + 16KB B)
// = 48KB -> 3 blocks/CU. One __syncthreads per k-step (stage next buffer,
// compute current, barrier); inter-block overlap hides the vmcnt drain.
// A LDS layout: row r (128B = 8 x 16B units), unit XOR-swizzled p = u^(r&7).
// DMA dest must be linear -> swizzle applied on the per-lane GLOBAL source
// address instead (same involution on read). B staging is a pure linear
// 16KB copy thanks to fragment-major WtF; B ds_read = base + lane*16
// (conflict-free).
__global__ __launch_bounds__(256) void gemm_tanh_kernel(
    const float* __restrict__ A, const short* __restrict__ WtF,
    unsigned short* __restrict__ H) {
  __shared__ __align__(16) float As[2][64 * 32];    // 2 x 8KB
  __shared__ __align__(16) short Bs[2][256 * 32];   // 2 x 16KB
  const int tid = threadIdx.x;
  const int wave = tid >> 6, lane = tid & 63;
  const int quad = lane >> 4, l16 = lane & 15;
  const int row0 = blockIdx.x * 64;

  f32x4 acc[4][4];   // [m][j]: rows m*16.., cols wave*64 + j*16..
  #pragma unroll
  for (int m = 0; m < 4; ++m)
    #pragma unroll
    for (int j = 0; j < 4; ++j) acc[m][j] = (f32x4){0.f, 0.f, 0.f, 0.f};

  // --- staging geometry (per thread, constant across steps) ---
  // A: wave w stages rows w*16 + i*8 + (lane>>3), 16B unit (lane&7);
  //    source unit pre-swizzled: (lane&7) ^ (lane>>3)  [(r&7) == lane>>3]
  const int ar_lo = wave * 16 + (lane >> 3);          // + i*8
  const int aswz = (lane & 7) ^ (lane >> 3);
  const float* asrc0 = A + (size_t)min(row0 + ar_lo,     M_NODES - 1) * K_IN + aswz * 4;
  const float* asrc1 = A + (size_t)min(row0 + ar_lo + 8, M_NODES - 1) * K_IN + aswz * 4;
  // B: 16KB/step linear copy; thread covers 16B units c = i*256 + tid
  const short* bsrc = WtF + (size_t)tid * 8;

  #define STAGE(ks, b)                                                         \
    do {                                                                       \
      __builtin_amdgcn_global_load_lds(                                        \
          (GLOBAL_AS const void*)(asrc0 + (ks) * 32),                          \
          (LDS_AS void*)&As[b][(wave * 16 + 0) * 32], 16, 0, 0);               \
      __builtin_amdgcn_global_load_lds(                                        \
          (GLOBAL_AS const void*)(asrc1 + (ks) * 32),                          \
          (LDS_AS void*)&As[b][(wave * 16 + 8) * 32], 16, 0, 0);               \
      _Pragma("unroll")                                                        \
      for (int i = 0; i < 4; ++i) {                                            \
        __builtin_amdgcn_global_load_lds(                                      \
            (GLOBAL_AS const void*)(bsrc + (size_t)(ks) * 8192 + i * 2048),    \
            (LDS_AS void*)&Bs[b][(i * 256 + wave * 64) * 8], 16, 0, 0);        \
      }                                                                        \
    } while (0)

  STAGE(0, 0);
  __syncthreads();

  int b = 0;
  for (int ks = 0; ks < 16; ++ks) {
    if (ks < 15) STAGE(ks + 1, b ^ 1);
    // --- compute buffer b ---
    bf16x8 bf[4];
    #pragma unroll
    for (int j = 0; j < 4; ++j)
      bf[j] = *(const bf16x8*)&Bs[b][((wave * 4 + j) * 64 + lane) * 8];
    #pragma unroll
    for (int m = 0; m < 4; ++m) {
      int row = m * 16 + l16;
      f32x4 lo = *(const f32x4*)&As[b][row * 32 + (((quad * 2 + 0) ^ (l16 & 7)) * 4)];
      f32x4 hi = *(const f32x4*)&As[b][row * 32 + (((quad * 2 + 1) ^ (l16 & 7)) * 4)];
      bf16x8 af = cvt8(lo, hi);
      #pragma unroll
      for (int j = 0; j < 4; ++j)
        acc[m][j] = __builtin_amdgcn_mfma_f32_16x16x32_bf16(af, bf[j], acc[m][j], 0, 0, 0);
    }
    __syncthreads();
    b ^= 1;
  }
  #undef STAGE

  // ---- epilogue: row = row0 + m*16 + quad*4 + rr, col = wave*64 + j*16 + l16
  #pragma unroll
  for (int m = 0; m < 4; ++m) {
    #pragma unroll
    for (int rr = 0; rr < 4; ++rr) {
      int row = row0 + m * 16 + quad * 4 + rr;
      if (row < M_NODES) {
        #pragma unroll
        for (int j = 0; j < 4; ++j) {
          H[(size_t)row * N_OUT + wave * 64 + j * 16 + l16] =
              f2bf_u(fast_tanh(acc[m][j][rr]));
        }
      }
    }
  }
}

// y[i,:] = sum_e vals[e]*x[col[e],:], x bf16 [M,256]. One wave/row; lane holds
// 4 features (8B/edge/lane -> full 512B row per edge, coalesced).
// Edge metadata (col/vals) loaded once per 64-edge chunk as a per-lane
// vector load, broadcast via __shfl; gathers issued 16-deep.
__global__ __launch_bounds__(256) void spmm_bf_bf(
    const int* __restrict__ rp, const int* __restrict__ colv,
    const float* __restrict__ vals, const unsigned short* __restrict__ x,
    unsigned short* __restrict__ y) {
  int w = (blockIdx.x * 256 + threadIdx.x) >> 6;
  int lane = threadIdx.x & 63;
  int i = __builtin_amdgcn_readfirstlane(w);
  int s = rp[i], e = rp[i + 1];
  float a0 = 0.f, a1 = 0.f, a2 = 0.f, a3 = 0.f;
  const unsigned short* xl = x + lane * 4;
  for (int base = s; base < e; base += 64) {
    int nn = min(e - base, 64);
    int tl = min(base + lane, e - 1);          // clamped: lanes >= nn unused
    int c_l = colv[tl];
    float v_l = vals[tl];
    int tt = 0;
    for (; tt + 16 <= nn; tt += 16) {
      ushort4 xv[16]; float vv[16];
      #pragma unroll
      for (int j = 0; j < 16; ++j) {
        int c = __shfl(c_l, tt + j);
        vv[j] = __shfl(v_l, tt + j);
        xv[j] = *(const ushort4*)(xl + (size_t)c * N_OUT);
      }
      #pragma unroll
      for (int j = 0; j < 16; ++j) {
        a0 += vv[j] * bfu2f(xv[j].x); a1 += vv[j] * bfu2f(xv[j].y);
        a2 += vv[j] * bfu2f(xv[j].z); a3 += vv[j] * bfu2f(xv[j].w);
      }
    }
    for (; tt + 8 <= nn; tt += 8) {
      ushort4 xv[8]; float vv[8];
      #pragma unroll
      for (int j = 0; j < 8; ++j) {
        int c = __shfl(c_l, tt + j);
        vv[j] = __shfl(v_l, tt + j);
        xv[j] = *(const ushort4*)(xl + (size_t)c * N_OUT);
      }
      #pragma unroll
      for (int j = 0; j < 8; ++j) {
        a0 += vv[j] * bfu2f(xv[j].x); a1 += vv[j] * bfu2f(xv[j].y);
        a2 += vv[j] * bfu2f(xv[j].z); a3 += vv[j] * bfu2f(xv[j].w);
      }
    }
    for (; tt + 4 <= nn; tt += 4) {
      ushort4 xv[4]; float vv[4];
      #pragma unroll
      for (int j = 0; j < 4; ++j) {
        int c = __shfl(c_l, tt + j);
        vv[j] = __shfl(v_l, tt + j);
        xv[j] = *(const ushort4*)(xl + (size_t)c * N_OUT);
      }
      #pragma unroll
      for (int j = 0; j < 4; ++j) {
        a0 += vv[j] * bfu2f(xv[j].x); a1 += vv[j] * bfu2f(xv[j].y);
        a2 += vv[j] * bfu2f(xv[j].z); a3 += vv[j] * bfu2f(xv[j].w);
      }
    }
    for (; tt < nn; ++tt) {
      int c = __shfl(c_l, tt);
      float v = __shfl(v_l, tt);
      ushort4 xv = *(const ushort4*)(xl + (size_t)c * N_OUT);
      a0 += v * bfu2f(xv.x); a1 += v * bfu2f(xv.y);
      a2 += v * bfu2f(xv.z); a3 += v * bfu2f(xv.w);
    }
  }
  ushort4 o;
  o.x = f2bf_u(a0); o.y = f2bf_u(a1); o.z = f2bf_u(a2); o.w = f2bf_u(a3);
  *(ushort4*)(y + (size_t)i * N_OUT + lane * 4) = o;
}

// same but f32 output (final layer writes d_out)
__global__ __launch_bounds__(256) void spmm_bf_f32(
    const int* __restrict__ rp, const int* __restrict__ colv,
    const float* __restrict__ vals, const unsigned short* __restrict__ x,
    float* __restrict__ y) {
  int w = (blockIdx.x * 256 + threadIdx.x) >> 6;
  int lane = threadIdx.x & 63;
  int i = __builtin_amdgcn_readfirstlane(w);
  int s = rp[i], e = rp[i + 1];
  float a0 = 0.f, a1 = 0.f, a2 = 0.f, a3 = 0.f;
  const unsigned short* xl = x + lane * 4;
  for (int base = s; base < e; base += 64) {
    int nn = min(e - base, 64);
    int tl = min(base + lane, e - 1);
    int c_l = colv[tl];
    float v_l = vals[tl];
    int tt = 0;
    for (; tt + 16 <= nn; tt += 16) {
      ushort4 xv[16]; float vv[16];
      #pragma unroll
      for (int j = 0; j < 16; ++j) {
        int c = __shfl(c_l, tt + j);
        vv[j] = __shfl(v_l, tt + j);
        xv[j] = *(const ushort4*)(xl + (size_t)c * N_OUT);
      }
      #pragma unroll
      for (int j = 0; j < 16; ++j) {
        a0 += vv[j] * bfu2f(xv[j].x); a1 += vv[j] * bfu2f(xv[j].y);
        a2 += vv[j] * bfu2f(xv[j].z); a3 += vv[j] * bfu2f(xv[j].w);
      }
    }
    for (; tt + 8 <= nn; tt += 8) {
      ushort4 xv[8]; float vv[8];
      #pragma unroll
      for (int j = 0; j < 8; ++j) {
        int c = __shfl(c_l, tt + j);
        vv[j] = __shfl(v_l, tt + j);
        xv[j] = *(const ushort4*)(xl + (size_t)c * N_OUT);
      }
      #pragma unroll
      for (int j = 0; j < 8; ++j) {
        a0 += vv[j] * bfu2f(xv[j].x); a1 += vv[j] * bfu2f(xv[j].y);
        a2 += vv[j] * bfu2f(xv[j].z); a3 += vv[j] * bfu2f(xv[j].w);
      }
    }
    for (; tt + 4 <= nn; tt += 4) {
      ushort4 xv[4]; float vv[4];
      #pragma unroll
      for (int j = 0; j < 4; ++j) {
        int c = __shfl(c_l, tt + j);
        vv[j] = __shfl(v_l, tt + j);
        xv[j] = *(const ushort4*)(xl + (size_t)c * N_OUT);
      }
      #pragma unroll
      for (int j = 0; j < 4; ++j) {
        a0 += vv[j] * bfu2f(xv[j].x); a1 += vv[j] * bfu2f(xv[j].y);
        a2 += vv[j] * bfu2f(xv[j].z); a3 += vv[j] * bfu2f(xv[j].w);
      }
    }
    for (; tt < nn; ++tt) {
      int c = __shfl(c_l, tt);
      float v = __shfl(v_l, tt);
      ushort4 xv = *(const ushort4*)(xl + (size_t)c * N_OUT);
      a0 += v * bfu2f(xv.x); a1 += v * bfu2f(xv.y);
      a2 += v * bfu2f(xv.z); a3 += v * bfu2f(xv.w);
    }
  }
  float4 o = {a0, a1, a2, a3};
  *(float4*)(y + (size_t)i * N_OUT + lane * 4) = o;
}

extern "C" void kernel_launch(void* const* d_in, const int* in_sizes, int n_in,
                              void* d_out, int out_size, void* d_ws, size_t ws_size,
                              hipStream_t stream) {
  const float* features = (const float*)d_in[0];
  const float* weight   = (const float*)d_in[1];
  const int*   row      = (const int*)d_in[2];
  const int*   col      = (const int*)d_in[3];
  const float* vals     = (const float*)d_in[4];
  float* out = (float*)d_out;

  char* ws = (char*)d_ws;
  const size_t HB = (size_t)M_NODES * N_OUT * 2;   // 51,200,000 bf16 H
  const size_t RPB = 400016;                        // 100001 ints padded
  unsigned short* H  = (unsigned short*)ws;
  unsigned short* y1 = (unsigned short*)(ws + HB);
  int*   rp = (int*)(ws + 2 * HB);
  short* Wt = (short*)(ws + 2 * HB + RPB);
  // total need: 2*51.2MB + 400016 + 262144 = 103,062,160 B (fits)

  prep_w_kernel<<<64, 256, 0, stream>>>(weight, Wt);
  build_rp_kernel<<<(M_NODES + 1 + 255) / 256, 256, 0, stream>>>(row, rp);
  // 64 rows/block, 256 cols, 1563 blocks
  gemm_tanh_kernel<<<(M_NODES + 63) / 64, 256, 0, stream>>>(features, Wt, H);
  spmm_bf_bf<<<25000, 256, 0, stream>>>(rp, col, vals, H, y1);
  spmm_bf_f32<<<25000, 256, 0, stream>>>(rp, col, vals, y1, out);
}

// Round 7
// 580.176 us; speedup vs baseline: 1.0676x; 1.0033x over previous
//
#include <hip/hip_runtime.h>
#include <hip/hip_bf16.h>

#define M_NODES 100000
#define N_EDGES 1600000
#define K_IN 512
#define N_OUT 256

typedef short bf16x8 __attribute__((ext_vector_type(8)));
typedef float f32x4 __attribute__((ext_vector_type(4)));

#define GLOBAL_AS __attribute__((address_space(1)))
#define LDS_AS __attribute__((address_space(3)))

__device__ inline unsigned short f2bf_u(float f) {
  union { float f; unsigned u; } x; x.f = f;
  unsigned r = x.u + 0x7FFFu + ((x.u >> 16) & 1u);
  return (unsigned short)(r >> 16);
}
__device__ inline float bfu2f(unsigned short h) {
  union { unsigned u; float f; } x; x.u = ((unsigned)h) << 16;
  return x.f;
}
// tanh(x) = sign(x) * (1-z)/(1+z), z = exp(-2|x|). ~7 VALU + 1 trans.
__device__ inline float fast_tanh(float x) {
  float ax = __builtin_fabsf(x);
  float z = __expf(-2.0f * ax);
  float t = (1.0f - z) * __builtin_amdgcn_rcpf(1.0f + z);
  return __builtin_copysignf(t, x);
}
// pack 8 f32 -> bf16x8 via v_cvt_pk_bf16_f32 (dst.lo = src0, RTNE)
__device__ inline bf16x8 cvt8(f32x4 lo, f32x4 hi) {
  union { unsigned u[4]; bf16x8 v; } r;
  asm("v_cvt_pk_bf16_f32 %0, %1, %2" : "=v"(r.u[0]) : "v"(lo[0]), "v"(lo[1]));
  asm("v_cvt_pk_bf16_f32 %0, %1, %2" : "=v"(r.u[1]) : "v"(lo[2]), "v"(lo[3]));
  asm("v_cvt_pk_bf16_f32 %0, %1, %2" : "=v"(r.u[2]) : "v"(hi[0]), "v"(hi[1]));
  asm("v_cvt_pk_bf16_f32 %0, %1, %2" : "=v"(r.u[3]) : "v"(hi[2]), "v"(hi[3]));
  return r.v;
}

// weight [512][256] f32 -> fragment-major bf16:
// wt[((ks*16+nt)*64 + lane)*8 + j] = bf16(w[ks*32+quad*8+j][nt*16+l16])
// so a wave's B fragment (ks,nt) is 1KB CONTIGUOUS: base + lane*16B, and a
// k-step's 16 fragments are one linear 16KB range (DMA-stageable as a copy).
__global__ void prep_w_kernel(const float* __restrict__ w, short* __restrict__ wt) {
  int frag = blockIdx.x * 256 + threadIdx.x;   // 16384 frags (64 blocks)
  int lane = frag & 63;
  int fi = frag >> 6;                          // ks*16 + nt
  int ks = fi >> 4, nt = fi & 15;
  int quad = lane >> 4, l16 = lane & 15;
  int n = nt * 16 + l16;
  int k0 = ks * 32 + quad * 8;
  #pragma unroll
  for (int j = 0; j < 8; ++j)
    wt[(size_t)frag * 8 + j] = (short)f2bf_u(w[(size_t)(k0 + j) * N_OUT + n]);
}

// row_ptr[r] = lower_bound(row, r) over sorted row[] (COO -> CSR)
__global__ void build_rp_kernel(const int* __restrict__ row, int* __restrict__ rp) {
  int r = blockIdx.x * 256 + threadIdx.x;
  if (r > M_NODES) return;
  int lo = 0, hi = N_EDGES;
  while (lo < hi) {
    int mid = (lo + hi) >> 1;
    if (row[mid] < r) lo = mid + 1; else hi = mid;
  }
  rp[r] = lo;
}

// H = bf16(tanh(A @ W)). A fp32 [M,512], WtF fragment-major bf16.
// m97-style memory-bound pipeline: ALL staging via global_load_lds width-16.
// BM=64 x BN=256 (A read ONCE), BK=32, 256 thr / 4 waves, wave owns 64 cols,
// acc[4][4]. LDS double-buffered 2x(8KB A fp32 + 16KB B) = 48KB -> 3
// blocks/CU. One __syncthreads per k-step. A LDS 16B-unit XOR swizzle via
// pre-swizzled GLOBAL source (linear DMA dest); B staging is a pure linear
// copy (fragment-major WtF), B ds_read = base + lane*16 (conflict-free).
__global__ __launch_bounds__(256) void gemm_tanh_kernel(
    const float* __restrict__ A, const short* __restrict__ WtF,
    unsigned short* __restrict__ H) {
  __shared__ __align__(16) float As[2][64 * 32];    // 2 x 8KB
  __shared__ __align__(16) short Bs[2][256 * 32];   // 2 x 16KB
  const int tid = threadIdx.x;
  const int wave = tid >> 6, lane = tid & 63;
  const int quad = lane >> 4, l16 = lane & 15;
  const int row0 = blockIdx.x * 64;

  f32x4 acc[4][4];   // [m][j]: rows m*16.., cols wave*64 + j*16..
  #pragma unroll
  for (int m = 0; m < 4; ++m)
    #pragma unroll
    for (int j = 0; j < 4; ++j) acc[m][j] = (f32x4){0.f, 0.f, 0.f, 0.f};

  // --- staging geometry (per thread, constant across steps) ---
  const int ar_lo = wave * 16 + (lane >> 3);          // + i*8
  const int aswz = (lane & 7) ^ (lane >> 3);
  const float* asrc0 = A + (size_t)min(row0 + ar_lo,     M_NODES - 1) * K_IN + aswz * 4;
  const float* asrc1 = A + (size_t)min(row0 + ar_lo + 8, M_NODES - 1) * K_IN + aswz * 4;
  const short* bsrc = WtF + (size_t)tid * 8;

  #define STAGE(ks, b)                                                         \
    do {                                                                       \
      __builtin_amdgcn_global_load_lds(                                        \
          (GLOBAL_AS const void*)(asrc0 + (ks) * 32),                          \
          (LDS_AS void*)&As[b][(wave * 16 + 0) * 32], 16, 0, 0);               \
      __builtin_amdgcn_global_load_lds(                                        \
          (GLOBAL_AS const void*)(asrc1 + (ks) * 32),                          \
          (LDS_AS void*)&As[b][(wave * 16 + 8) * 32], 16, 0, 0);               \
      _Pragma("unroll")                                                        \
      for (int i = 0; i < 4; ++i) {                                            \
        __builtin_amdgcn_global_load_lds(                                      \
            (GLOBAL_AS const void*)(bsrc + (size_t)(ks) * 8192 + i * 2048),    \
            (LDS_AS void*)&Bs[b][(i * 256 + wave * 64) * 8], 16, 0, 0);        \
      }                                                                        \
    } while (0)

  STAGE(0, 0);
  __syncthreads();

  int b = 0;
  for (int ks = 0; ks < 16; ++ks) {
    if (ks < 15) STAGE(ks + 1, b ^ 1);
    // --- compute buffer b ---
    bf16x8 bf[4];
    #pragma unroll
    for (int j = 0; j < 4; ++j)
      bf[j] = *(const bf16x8*)&Bs[b][((wave * 4 + j) * 64 + lane) * 8];
    #pragma unroll
    for (int m = 0; m < 4; ++m) {
      int row = m * 16 + l16;
      f32x4 lo = *(const f32x4*)&As[b][row * 32 + (((quad * 2 + 0) ^ (l16 & 7)) * 4)];
      f32x4 hi = *(const f32x4*)&As[b][row * 32 + (((quad * 2 + 1) ^ (l16 & 7)) * 4)];
      bf16x8 af = cvt8(lo, hi);
      #pragma unroll
      for (int j = 0; j < 4; ++j)
        acc[m][j] = __builtin_amdgcn_mfma_f32_16x16x32_bf16(af, bf[j], acc[m][j], 0, 0, 0);
    }
    __syncthreads();
    b ^= 1;
  }
  #undef STAGE

  // ---- epilogue: row = row0 + m*16 + quad*4 + rr, col = wave*64 + j*16 + l16
  #pragma unroll
  for (int m = 0; m < 4; ++m) {
    #pragma unroll
    for (int rr = 0; rr < 4; ++rr) {
      int row = row0 + m * 16 + quad * 4 + rr;
      if (row < M_NODES) {
        #pragma unroll
        for (int j = 0; j < 4; ++j) {
          H[(size_t)row * N_OUT + wave * 64 + j * 16 + l16] =
              f2bf_u(fast_tanh(acc[m][j][rr]));
        }
      }
    }
  }
}

// y[i,:] = sum_e vals[e]*x[col[e],:], x bf16 [M,256]. One wave/row; lane holds
// 4 features (8B/edge/lane -> full 512B row per edge, coalesced).
// R6 forensics: declared 16-deep bursts collapsed to VGPR=32 (compiler's
// occupancy heuristic interleaved waits) -> MLP ~4, latency-bound at 126us.
// Fix: sched_barrier(0) between the ISSUE cluster and the CONSUME cluster
// pins all 16 gathers above all consumes -> 16 results simultaneously live
// -> allocator must hold them -> true MLP=16. launch_bounds(256,1) relaxes
// the VGPR cap so this doesn't spill.
__global__ __launch_bounds__(256, 1) void spmm_bf_bf(
    const int* __restrict__ rp, const int* __restrict__ colv,
    const float* __restrict__ vals, const unsigned short* __restrict__ x,
    unsigned short* __restrict__ y) {
  int w = (blockIdx.x * 256 + threadIdx.x) >> 6;
  int lane = threadIdx.x & 63;
  int i = __builtin_amdgcn_readfirstlane(w);
  int s = rp[i], e = rp[i + 1];
  float a0 = 0.f, a1 = 0.f, a2 = 0.f, a3 = 0.f;
  const unsigned short* xl = x + lane * 4;
  for (int base = s; base < e; base += 64) {
    int nn = min(e - base, 64);
    int tl = min(base + lane, e - 1);          // clamped: lanes >= nn unused
    int c_l = colv[tl];
    float v_l = vals[tl];
    int tt = 0;
    for (; tt + 16 <= nn; tt += 16) {
      ushort4 xv[16]; float vv[16];
      #pragma unroll
      for (int j = 0; j < 16; ++j) {
        int c = __shfl(c_l, tt + j);
        vv[j] = __shfl(v_l, tt + j);
        xv[j] = *(const ushort4*)(xl + (size_t)c * N_OUT);
      }
      __builtin_amdgcn_sched_barrier(0);
      #pragma unroll
      for (int j = 0; j < 16; ++j) {
        a0 += vv[j] * bfu2f(xv[j].x); a1 += vv[j] * bfu2f(xv[j].y);
        a2 += vv[j] * bfu2f(xv[j].z); a3 += vv[j] * bfu2f(xv[j].w);
      }
    }
    for (; tt + 8 <= nn; tt += 8) {
      ushort4 xv[8]; float vv[8];
      #pragma unroll
      for (int j = 0; j < 8; ++j) {
        int c = __shfl(c_l, tt + j);
        vv[j] = __shfl(v_l, tt + j);
        xv[j] = *(const ushort4*)(xl + (size_t)c * N_OUT);
      }
      __builtin_amdgcn_sched_barrier(0);
      #pragma unroll
      for (int j = 0; j < 8; ++j) {
        a0 += vv[j] * bfu2f(xv[j].x); a1 += vv[j] * bfu2f(xv[j].y);
        a2 += vv[j] * bfu2f(xv[j].z); a3 += vv[j] * bfu2f(xv[j].w);
      }
    }
    for (; tt + 4 <= nn; tt += 4) {
      ushort4 xv[4]; float vv[4];
      #pragma unroll
      for (int j = 0; j < 4; ++j) {
        int c = __shfl(c_l, tt + j);
        vv[j] = __shfl(v_l, tt + j);
        xv[j] = *(const ushort4*)(xl + (size_t)c * N_OUT);
      }
      __builtin_amdgcn_sched_barrier(0);
      #pragma unroll
      for (int j = 0; j < 4; ++j) {
        a0 += vv[j] * bfu2f(xv[j].x); a1 += vv[j] * bfu2f(xv[j].y);
        a2 += vv[j] * bfu2f(xv[j].z); a3 += vv[j] * bfu2f(xv[j].w);
      }
    }
    for (; tt < nn; ++tt) {
      int c = __shfl(c_l, tt);
      float v = __shfl(v_l, tt);
      ushort4 xv = *(const ushort4*)(xl + (size_t)c * N_OUT);
      a0 += v * bfu2f(xv.x); a1 += v * bfu2f(xv.y);
      a2 += v * bfu2f(xv.z); a3 += v * bfu2f(xv.w);
    }
  }
  ushort4 o;
  o.x = f2bf_u(a0); o.y = f2bf_u(a1); o.z = f2bf_u(a2); o.w = f2bf_u(a3);
  *(ushort4*)(y + (size_t)i * N_OUT + lane * 4) = o;
}

// same but f32 output (final layer writes d_out)
__global__ __launch_bounds__(256, 1) void spmm_bf_f32(
    const int* __restrict__ rp, const int* __restrict__ colv,
    const float* __restrict__ vals, const unsigned short* __restrict__ x,
    float* __restrict__ y) {
  int w = (blockIdx.x * 256 + threadIdx.x) >> 6;
  int lane = threadIdx.x & 63;
  int i = __builtin_amdgcn_readfirstlane(w);
  int s = rp[i], e = rp[i + 1];
  float a0 = 0.f, a1 = 0.f, a2 = 0.f, a3 = 0.f;
  const unsigned short* xl = x + lane * 4;
  for (int base = s; base < e; base += 64) {
    int nn = min(e - base, 64);
    int tl = min(base + lane, e - 1);
    int c_l = colv[tl];
    float v_l = vals[tl];
    int tt = 0;
    for (; tt + 16 <= nn; tt += 16) {
      ushort4 xv[16]; float vv[16];
      #pragma unroll
      for (int j = 0; j < 16; ++j) {
        int c = __shfl(c_l, tt + j);
        vv[j] = __shfl(v_l, tt + j);
        xv[j] = *(const ushort4*)(xl + (size_t)c * N_OUT);
      }
      __builtin_amdgcn_sched_barrier(0);
      #pragma unroll
      for (int j = 0; j < 16; ++j) {
        a0 += vv[j] * bfu2f(xv[j].x); a1 += vv[j] * bfu2f(xv[j].y);
        a2 += vv[j] * bfu2f(xv[j].z); a3 += vv[j] * bfu2f(xv[j].w);
      }
    }
    for (; tt + 8 <= nn; tt += 8) {
      ushort4 xv[8]; float vv[8];
      #pragma unroll
      for (int j = 0; j < 8; ++j) {
        int c = __shfl(c_l, tt + j);
        vv[j] = __shfl(v_l, tt + j);
        xv[j] = *(const ushort4*)(xl + (size_t)c * N_OUT);
      }
      __builtin_amdgcn_sched_barrier(0);
      #pragma unroll
      for (int j = 0; j < 8; ++j) {
        a0 += vv[j] * bfu2f(xv[j].x); a1 += vv[j] * bfu2f(xv[j].y);
        a2 += vv[j] * bfu2f(xv[j].z); a3 += vv[j] * bfu2f(xv[j].w);
      }
    }
    for (; tt + 4 <= nn; tt += 4) {
      ushort4 xv[4]; float vv[4];
      #pragma unroll
      for (int j = 0; j < 4; ++j) {
        int c = __shfl(c_l, tt + j);
        vv[j] = __shfl(v_l, tt + j);
        xv[j] = *(const ushort4*)(xl + (size_t)c * N_OUT);
      }
      __builtin_amdgcn_sched_barrier(0);
      #pragma unroll
      for (int j = 0; j < 4; ++j) {
        a0 += vv[j] * bfu2f(xv[j].x); a1 += vv[j] * bfu2f(xv[j].y);
        a2 += vv[j] * bfu2f(xv[j].z); a3 += vv[j] * bfu2f(xv[j].w);
      }
    }
    for (; tt < nn; ++tt) {
      int c = __shfl(c_l, tt);
      float v = __shfl(v_l, tt);
      ushort4 xv = *(const ushort4*)(xl + (size_t)c * N_OUT);
      a0 += v * bfu2f(xv.x); a1 += v * bfu2f(xv.y);
      a2 += v * bfu2f(xv.z); a3 += v * bfu2f(xv.w);
    }
  }
  float4 o = {a0, a1, a2, a3};
  *(float4*)(y + (size_t)i * N_OUT + lane * 4) = o;
}

extern "C" void kernel_launch(void* const* d_in, const int* in_sizes, int n_in,
                              void* d_out, int out_size, void* d_ws, size_t ws_size,
                              hipStream_t stream) {
  const float* features = (const float*)d_in[0];
  const float* weight   = (const float*)d_in[1];
  const int*   row      = (const int*)d_in[2];
  const int*   col      = (const int*)d_in[3];
  const float* vals     = (const float*)d_in[4];
  float* out = (float*)d_out;

  char* ws = (char*)d_ws;
  const size_t HB = (size_t)M_NODES * N_OUT * 2;   // 51,200,000 bf16 H
  const size_t RPB = 400016;                        // 100001 ints padded
  unsigned short* H  = (unsigned short*)ws;
  unsigned short* y1 = (unsigned short*)(ws + HB);
  int*   rp = (int*)(ws + 2 * HB);
  short* Wt = (short*)(ws + 2 * HB + RPB);
  // total need: 2*51.2MB + 400016 + 262144 = 103,062,160 B (fits)

  prep_w_kernel<<<64, 256, 0, stream>>>(weight, Wt);
  build_rp_kernel<<<(M_NODES + 1 + 255) / 256, 256, 0, stream>>>(row, rp);
  // 64 rows/block, 256 cols, 1563 blocks
  gemm_tanh_kernel<<<(M_NODES + 63) / 64, 256, 0, stream>>>(features, Wt, H);
  spmm_bf_bf<<<25000, 256, 0, stream>>>(rp, col, vals, H, y1);
  spmm_bf_f32<<<25000, 256, 0, stream>>>(rp, col, vals, y1, out);
}

// Round 8
// 575.727 us; speedup vs baseline: 1.0758x; 1.0077x over previous
//
#include <hip/hip_runtime.h>
#include <hip/hip_bf16.h>

#define M_NODES 100000
#define N_EDGES 1600000
#define K_IN 512
#define N_OUT 256

typedef short bf16x8 __attribute__((ext_vector_type(8)));
typedef float f32x4 __attribute__((ext_vector_type(4)));

#define GLOBAL_AS __attribute__((address_space(1)))
#define LDS_AS __attribute__((address_space(3)))

__device__ inline unsigned short f2bf_u(float f) {
  union { float f; unsigned u; } x; x.f = f;
  unsigned r = x.u + 0x7FFFu + ((x.u >> 16) & 1u);
  return (unsigned short)(r >> 16);
}
__device__ inline float bfu2f(unsigned short h) {
  union { unsigned u; float f; } x; x.u = ((unsigned)h) << 16;
  return x.f;
}
// tanh(x) = sign(x) * (1-z)/(1+z), z = exp(-2|x|). ~7 VALU + 1 trans.
__device__ inline float fast_tanh(float x) {
  float ax = __builtin_fabsf(x);
  float z = __expf(-2.0f * ax);
  float t = (1.0f - z) * __builtin_amdgcn_rcpf(1.0f + z);
  return __builtin_copysignf(t, x);
}
// pack 8 f32 -> bf16x8 via v_cvt_pk_bf16_f32 (dst.lo = src0, RTNE)
__device__ inline bf16x8 cvt8(f32x4 lo, f32x4 hi) {
  union { unsigned u[4]; bf16x8 v; } r;
  asm("v_cvt_pk_bf16_f32 %0, %1, %2" : "=v"(r.u[0]) : "v"(lo[0]), "v"(lo[1]));
  asm("v_cvt_pk_bf16_f32 %0, %1, %2" : "=v"(r.u[1]) : "v"(lo[2]), "v"(lo[3]));
  asm("v_cvt_pk_bf16_f32 %0, %1, %2" : "=v"(r.u[2]) : "v"(hi[0]), "v"(hi[1]));
  asm("v_cvt_pk_bf16_f32 %0, %1, %2" : "=v"(r.u[3]) : "v"(hi[2]), "v"(hi[3]));
  return r.v;
}

// weight [512][256] f32 -> fragment-major bf16:
// wt[((ks*16+nt)*64 + lane)*8 + j] = bf16(w[ks*32+quad*8+j][nt*16+l16])
// so a wave's B fragment (ks,nt) is 1KB CONTIGUOUS: base + lane*16B, and a
// k-step's 16 fragments are one linear 16KB range (DMA-stageable as a copy).
__global__ void prep_w_kernel(const float* __restrict__ w, short* __restrict__ wt) {
  int frag = blockIdx.x * 256 + threadIdx.x;   // 16384 frags (64 blocks)
  int lane = frag & 63;
  int fi = frag >> 6;                          // ks*16 + nt
  int ks = fi >> 4, nt = fi & 15;
  int quad = lane >> 4, l16 = lane & 15;
  int n = nt * 16 + l16;
  int k0 = ks * 32 + quad * 8;
  #pragma unroll
  for (int j = 0; j < 8; ++j)
    wt[(size_t)frag * 8 + j] = (short)f2bf_u(w[(size_t)(k0 + j) * N_OUT + n]);
}

// row_ptr[r] = lower_bound(row, r) over sorted row[] (COO -> CSR)
__global__ void build_rp_kernel(const int* __restrict__ row, int* __restrict__ rp) {
  int r = blockIdx.x * 256 + threadIdx.x;
  if (r > M_NODES) return;
  int lo = 0, hi = N_EDGES;
  while (lo < hi) {
    int mid = (lo + hi) >> 1;
    if (row[mid] < r) lo = mid + 1; else hi = mid;
  }
  rp[r] = lo;
}

// H = bf16(tanh(A @ W)). A fp32 [M,512], WtF fragment-major bf16.
// m97-style memory-bound pipeline: ALL staging via global_load_lds width-16.
// BM=64 x BN=256 (A read ONCE), BK=32, 256 thr / 4 waves, wave owns 64 cols,
// acc[4][4]. LDS double-buffered 2x(8KB A fp32 + 16KB B) = 48KB -> 3
// blocks/CU. One __syncthreads per k-step. A LDS 16B-unit XOR swizzle via
// pre-swizzled GLOBAL source (linear DMA dest); B staging is a pure linear
// copy (fragment-major WtF), B ds_read = base + lane*16 (conflict-free).
__global__ __launch_bounds__(256) void gemm_tanh_kernel(
    const float* __restrict__ A, const short* __restrict__ WtF,
    unsigned short* __restrict__ H) {
  __shared__ __align__(16) float As[2][64 * 32];    // 2 x 8KB
  __shared__ __align__(16) short Bs[2][256 * 32];   // 2 x 16KB
  const int tid = threadIdx.x;
  const int wave = tid >> 6, lane = tid & 63;
  const int quad = lane >> 4, l16 = lane & 15;
  const int row0 = blockIdx.x * 64;

  f32x4 acc[4][4];   // [m][j]: rows m*16.., cols wave*64 + j*16..
  #pragma unroll
  for (int m = 0; m < 4; ++m)
    #pragma unroll
    for (int j = 0; j < 4; ++j) acc[m][j] = (f32x4){0.f, 0.f, 0.f, 0.f};

  // --- staging geometry (per thread, constant across steps) ---
  const int ar_lo = wave * 16 + (lane >> 3);          // + i*8
  const int aswz = (lane & 7) ^ (lane >> 3);
  const float* asrc0 = A + (size_t)min(row0 + ar_lo,     M_NODES - 1) * K_IN + aswz * 4;
  const float* asrc1 = A + (size_t)min(row0 + ar_lo + 8, M_NODES - 1) * K_IN + aswz * 4;
  const short* bsrc = WtF + (size_t)tid * 8;

  #define STAGE(ks, b)                                                         \
    do {                                                                       \
      __builtin_amdgcn_global_load_lds(                                        \
          (GLOBAL_AS const void*)(asrc0 + (ks) * 32),                          \
          (LDS_AS void*)&As[b][(wave * 16 + 0) * 32], 16, 0, 0);               \
      __builtin_amdgcn_global_load_lds(                                        \
          (GLOBAL_AS const void*)(asrc1 + (ks) * 32),                          \
          (LDS_AS void*)&As[b][(wave * 16 + 8) * 32], 16, 0, 0);               \
      _Pragma("unroll")                                                        \
      for (int i = 0; i < 4; ++i) {                                            \
        __builtin_amdgcn_global_load_lds(                                      \
            (GLOBAL_AS const void*)(bsrc + (size_t)(ks) * 8192 + i * 2048),    \
            (LDS_AS void*)&Bs[b][(i * 256 + wave * 64) * 8], 16, 0, 0);        \
      }                                                                        \
    } while (0)

  STAGE(0, 0);
  __syncthreads();

  int b = 0;
  for (int ks = 0; ks < 16; ++ks) {
    if (ks < 15) STAGE(ks + 1, b ^ 1);
    // --- compute buffer b ---
    bf16x8 bf[4];
    #pragma unroll
    for (int j = 0; j < 4; ++j)
      bf[j] = *(const bf16x8*)&Bs[b][((wave * 4 + j) * 64 + lane) * 8];
    #pragma unroll
    for (int m = 0; m < 4; ++m) {
      int row = m * 16 + l16;
      f32x4 lo = *(const f32x4*)&As[b][row * 32 + (((quad * 2 + 0) ^ (l16 & 7)) * 4)];
      f32x4 hi = *(const f32x4*)&As[b][row * 32 + (((quad * 2 + 1) ^ (l16 & 7)) * 4)];
      bf16x8 af = cvt8(lo, hi);
      #pragma unroll
      for (int j = 0; j < 4; ++j)
        acc[m][j] = __builtin_amdgcn_mfma_f32_16x16x32_bf16(af, bf[j], acc[m][j], 0, 0, 0);
    }
    __syncthreads();
    b ^= 1;
  }
  #undef STAGE

  // ---- epilogue: row = row0 + m*16 + quad*4 + rr, col = wave*64 + j*16 + l16
  #pragma unroll
  for (int m = 0; m < 4; ++m) {
    #pragma unroll
    for (int rr = 0; rr < 4; ++rr) {
      int row = row0 + m * 16 + quad * 4 + rr;
      if (row < M_NODES) {
        #pragma unroll
        for (int j = 0; j < 4; ++j) {
          H[(size_t)row * N_OUT + wave * 64 + j * 16 + l16] =
              f2bf_u(fast_tanh(acc[m][j][rr]));
        }
      }
    }
  }
}

// y[i,:] = sum_e vals[e]*x[col[e],:], x bf16 [M,256]. One wave/row; lane holds
// 4 features (8B/edge/lane -> full 512B row per edge, coalesced).
// R7 forensics: sched_barrier-pinned bursts STILL collapsed (VGPR=32 -> 16
// in-flight results physically impossible). Only mechanism the compiler
// cannot undo: asm volatile loads. Per 16-edge chunk: 16 global_load_dwordx2
// issued as strictly-ordered volatile asm, then asm s_waitcnt vmcnt(0) +
// sched_barrier(0) (guide rule #18), then consume. Chunk padded to 16: pad
// lanes clamp to the row's LAST col (gather hits L1/L2 -> near-free) with
// v=0 so they add nothing.
__global__ __launch_bounds__(256, 1) void spmm_bf_bf(
    const int* __restrict__ rp, const int* __restrict__ colv,
    const float* __restrict__ vals, const unsigned short* __restrict__ x,
    unsigned short* __restrict__ y) {
  int w = (blockIdx.x * 256 + threadIdx.x) >> 6;
  int lane = threadIdx.x & 63;
  int i = __builtin_amdgcn_readfirstlane(w);
  int s = rp[i], e = rp[i + 1];
  float a0 = 0.f, a1 = 0.f, a2 = 0.f, a3 = 0.f;
  const unsigned long long xb = (unsigned long long)(x) + (unsigned)(lane * 8);
  for (int k = s; k < e; k += 16) {
    int tl = min(k + lane, e - 1);
    int c_l = colv[tl];
    float v_l = (k + lane < e) ? vals[tl] : 0.f;
    unsigned long long pp[16];
    float vv[16];
    #pragma unroll
    for (int j = 0; j < 16; ++j) {
      int c = __shfl(c_l, j);
      vv[j] = __shfl(v_l, j);
      pp[j] = xb + ((unsigned long long)(unsigned)c << 9);
    }
    unsigned long long d[16];
    #pragma unroll
    for (int j = 0; j < 16; ++j)
      asm volatile("global_load_dwordx2 %0, %1, off" : "=v"(d[j]) : "v"(pp[j]));
    asm volatile("s_waitcnt vmcnt(0)" ::: "memory");
    __builtin_amdgcn_sched_barrier(0);
    #pragma unroll
    for (int j = 0; j < 16; ++j) {
      unsigned lo = (unsigned)d[j], hi = (unsigned)(d[j] >> 32);
      union { unsigned u; float f; } f0, f1, f2, f3;
      f0.u = lo << 16; f1.u = lo & 0xffff0000u;
      f2.u = hi << 16; f3.u = hi & 0xffff0000u;
      a0 += vv[j] * f0.f; a1 += vv[j] * f1.f;
      a2 += vv[j] * f2.f; a3 += vv[j] * f3.f;
    }
  }
  ushort4 o;
  o.x = f2bf_u(a0); o.y = f2bf_u(a1); o.z = f2bf_u(a2); o.w = f2bf_u(a3);
  *(ushort4*)(y + (size_t)i * N_OUT + lane * 4) = o;
}

// same but f32 output (final layer writes d_out)
__global__ __launch_bounds__(256, 1) void spmm_bf_f32(
    const int* __restrict__ rp, const int* __restrict__ colv,
    const float* __restrict__ vals, const unsigned short* __restrict__ x,
    float* __restrict__ y) {
  int w = (blockIdx.x * 256 + threadIdx.x) >> 6;
  int lane = threadIdx.x & 63;
  int i = __builtin_amdgcn_readfirstlane(w);
  int s = rp[i], e = rp[i + 1];
  float a0 = 0.f, a1 = 0.f, a2 = 0.f, a3 = 0.f;
  const unsigned long long xb = (unsigned long long)(x) + (unsigned)(lane * 8);
  for (int k = s; k < e; k += 16) {
    int tl = min(k + lane, e - 1);
    int c_l = colv[tl];
    float v_l = (k + lane < e) ? vals[tl] : 0.f;
    unsigned long long pp[16];
    float vv[16];
    #pragma unroll
    for (int j = 0; j < 16; ++j) {
      int c = __shfl(c_l, j);
      vv[j] = __shfl(v_l, j);
      pp[j] = xb + ((unsigned long long)(unsigned)c << 9);
    }
    unsigned long long d[16];
    #pragma unroll
    for (int j = 0; j < 16; ++j)
      asm volatile("global_load_dwordx2 %0, %1, off" : "=v"(d[j]) : "v"(pp[j]));
    asm volatile("s_waitcnt vmcnt(0)" ::: "memory");
    __builtin_amdgcn_sched_barrier(0);
    #pragma unroll
    for (int j = 0; j < 16; ++j) {
      unsigned lo = (unsigned)d[j], hi = (unsigned)(d[j] >> 32);
      union { unsigned u; float f; } f0, f1, f2, f3;
      f0.u = lo << 16; f1.u = lo & 0xffff0000u;
      f2.u = hi << 16; f3.u = hi & 0xffff0000u;
      a0 += vv[j] * f0.f; a1 += vv[j] * f1.f;
      a2 += vv[j] * f2.f; a3 += vv[j] * f3.f;
    }
  }
  float4 o = {a0, a1, a2, a3};
  *(float4*)(y + (size_t)i * N_OUT + lane * 4) = o;
}

extern "C" void kernel_launch(void* const* d_in, const int* in_sizes, int n_in,
                              void* d_out, int out_size, void* d_ws, size_t ws_size,
                              hipStream_t stream) {
  const float* features = (const float*)d_in[0];
  const float* weight   = (const float*)d_in[1];
  const int*   row      = (const int*)d_in[2];
  const int*   col      = (const int*)d_in[3];
  const float* vals     = (const float*)d_in[4];
  float* out = (float*)d_out;

  char* ws = (char*)d_ws;
  const size_t HB = (size_t)M_NODES * N_OUT * 2;   // 51,200,000 bf16 H
  const size_t RPB = 400016;                        // 100001 ints padded
  unsigned short* H  = (unsigned short*)ws;
  unsigned short* y1 = (unsigned short*)(ws + HB);
  int*   rp = (int*)(ws + 2 * HB);
  short* Wt = (short*)(ws + 2 * HB + RPB);
  // total need: 2*51.2MB + 400016 + 262144 = 103,062,160 B (fits)

  prep_w_kernel<<<64, 256, 0, stream>>>(weight, Wt);
  build_rp_kernel<<<(M_NODES + 1 + 255) / 256, 256, 0, stream>>>(row, rp);
  // 64 rows/block, 256 cols, 1563 blocks
  gemm_tanh_kernel<<<(M_NODES + 63) / 64, 256, 0, stream>>>(features, Wt, H);
  spmm_bf_bf<<<25000, 256, 0, stream>>>(rp, col, vals, H, y1);
  spmm_bf_f32<<<25000, 256, 0, stream>>>(rp, col, vals, y1, out);
}

// Round 9
// 572.734 us; speedup vs baseline: 1.0815x; 1.0052x over previous
//
#include <hip/hip_runtime.h>
#include <hip/hip_bf16.h>

#define M_NODES 100000
#define N_EDGES 1600000
#define K_IN 512
#define N_OUT 256

typedef short bf16x8 __attribute__((ext_vector_type(8)));
typedef float f32x4 __attribute__((ext_vector_type(4)));

#define GLOBAL_AS __attribute__((address_space(1)))
#define LDS_AS __attribute__((address_space(3)))

__device__ inline unsigned short f2bf_u(float f) {
  union { float f; unsigned u; } x; x.f = f;
  unsigned r = x.u + 0x7FFFu + ((x.u >> 16) & 1u);
  return (unsigned short)(r >> 16);
}
__device__ inline float bfu2f(unsigned short h) {
  union { unsigned u; float f; } x; x.u = ((unsigned)h) << 16;
  return x.f;
}
// tanh(x) = sign(x) * (1-z)/(1+z), z = exp(-2|x|). ~7 VALU + 1 trans.
__device__ inline float fast_tanh(float x) {
  float ax = __builtin_fabsf(x);
  float z = __expf(-2.0f * ax);
  float t = (1.0f - z) * __builtin_amdgcn_rcpf(1.0f + z);
  return __builtin_copysignf(t, x);
}
// pack 8 f32 -> bf16x8 via v_cvt_pk_bf16_f32 (dst.lo = src0, RTNE)
__device__ inline bf16x8 cvt8(f32x4 lo, f32x4 hi) {
  union { unsigned u[4]; bf16x8 v; } r;
  asm("v_cvt_pk_bf16_f32 %0, %1, %2" : "=v"(r.u[0]) : "v"(lo[0]), "v"(lo[1]));
  asm("v_cvt_pk_bf16_f32 %0, %1, %2" : "=v"(r.u[1]) : "v"(lo[2]), "v"(lo[3]));
  asm("v_cvt_pk_bf16_f32 %0, %1, %2" : "=v"(r.u[2]) : "v"(hi[0]), "v"(hi[1]));
  asm("v_cvt_pk_bf16_f32 %0, %1, %2" : "=v"(r.u[3]) : "v"(hi[2]), "v"(hi[3]));
  return r.v;
}

// weight [512][256] f32 -> fragment-major bf16:
// wt[((ks*16+nt)*64 + lane)*8 + j] = bf16(w[ks*32+quad*8+j][nt*16+l16])
// so a wave's B fragment (ks,nt) is 1KB CONTIGUOUS: base + lane*16B, and a
// k-step's 16 fragments are one linear 16KB range (DMA-stageable as a copy).
__global__ void prep_w_kernel(const float* __restrict__ w, short* __restrict__ wt) {
  int frag = blockIdx.x * 256 + threadIdx.x;   // 16384 frags (64 blocks)
  int lane = frag & 63;
  int fi = frag >> 6;                          // ks*16 + nt
  int ks = fi >> 4, nt = fi & 15;
  int quad = lane >> 4, l16 = lane & 15;
  int n = nt * 16 + l16;
  int k0 = ks * 32 + quad * 8;
  #pragma unroll
  for (int j = 0; j < 8; ++j)
    wt[(size_t)frag * 8 + j] = (short)f2bf_u(w[(size_t)(k0 + j) * N_OUT + n]);
}

// row_ptr[r] = lower_bound(row, r) over sorted row[] (COO -> CSR)
__global__ void build_rp_kernel(const int* __restrict__ row, int* __restrict__ rp) {
  int r = blockIdx.x * 256 + threadIdx.x;
  if (r > M_NODES) return;
  int lo = 0, hi = N_EDGES;
  while (lo < hi) {
    int mid = (lo + hi) >> 1;
    if (row[mid] < r) lo = mid + 1; else hi = mid;
  }
  rp[r] = lo;
}

// H = bf16(tanh(A @ W)). A fp32 [M,512], WtF fragment-major bf16.
// R8 post-mortem: R6's __syncthreads (implicit vmcnt(0)) right after
// STAGE(next) put the full staging round-trip on every k-step's critical
// path. T3/T4 fix: raw s_barrier + COUNTED vmcnt. 2-deep prefetch; per
// step the queue holds [stage(ks) 6 loads][stage(ks+1) 6 loads]; vmcnt(6)
// retires exactly stage(ks) while stage(ks+1) stays in flight across the
// barrier. STAGE(ks+2) into buffer b is issued only AFTER the post-compute
// barrier (no wave can still be reading b). sched_barrier(0) pins the
// boundaries (rule #18: compiler hoists reg-only ops past asm waitcnt).
__global__ __launch_bounds__(256) void gemm_tanh_kernel(
    const float* __restrict__ A, const short* __restrict__ WtF,
    unsigned short* __restrict__ H) {
  __shared__ __align__(16) float As[2][64 * 32];    // 2 x 8KB
  __shared__ __align__(16) short Bs[2][256 * 32];   // 2 x 16KB
  const int tid = threadIdx.x;
  const int wave = tid >> 6, lane = tid & 63;
  const int quad = lane >> 4, l16 = lane & 15;
  const int row0 = blockIdx.x * 64;

  f32x4 acc[4][4];   // [m][j]: rows m*16.., cols wave*64 + j*16..
  #pragma unroll
  for (int m = 0; m < 4; ++m)
    #pragma unroll
    for (int j = 0; j < 4; ++j) acc[m][j] = (f32x4){0.f, 0.f, 0.f, 0.f};

  // --- staging geometry (per thread, constant across steps) ---
  const int ar_lo = wave * 16 + (lane >> 3);          // + i*8
  const int aswz = (lane & 7) ^ (lane >> 3);
  const float* asrc0 = A + (size_t)min(row0 + ar_lo,     M_NODES - 1) * K_IN + aswz * 4;
  const float* asrc1 = A + (size_t)min(row0 + ar_lo + 8, M_NODES - 1) * K_IN + aswz * 4;
  const short* bsrc = WtF + (size_t)tid * 8;

  #define STAGE(ks, b)                                                         \
    do {                                                                       \
      __builtin_amdgcn_global_load_lds(                                        \
          (GLOBAL_AS const void*)(asrc0 + (ks) * 32),                          \
          (LDS_AS void*)&As[b][(wave * 16 + 0) * 32], 16, 0, 0);               \
      __builtin_amdgcn_global_load_lds(                                        \
          (GLOBAL_AS const void*)(asrc1 + (ks) * 32),                          \
          (LDS_AS void*)&As[b][(wave * 16 + 8) * 32], 16, 0, 0);               \
      _Pragma("unroll")                                                        \
      for (int i = 0; i < 4; ++i) {                                            \
        __builtin_amdgcn_global_load_lds(                                      \
            (GLOBAL_AS const void*)(bsrc + (size_t)(ks) * 8192 + i * 2048),    \
            (LDS_AS void*)&Bs[b][(i * 256 + wave * 64) * 8], 16, 0, 0);        \
      }                                                                        \
    } while (0)

  STAGE(0, 0);
  STAGE(1, 1);   // 12 loads outstanding

  int b = 0;
  #pragma unroll
  for (int ks = 0; ks < 16; ++ks) {
    // retire stage(ks); keep stage(ks+1)'s 6 loads in flight
    if (ks < 15) asm volatile("s_waitcnt vmcnt(6)" ::: "memory");
    else         asm volatile("s_waitcnt vmcnt(0)" ::: "memory");
    __builtin_amdgcn_s_barrier();          // all waves' stage(ks) landed
    __builtin_amdgcn_sched_barrier(0);
    // --- compute buffer b ---
    bf16x8 bf[4];
    #pragma unroll
    for (int j = 0; j < 4; ++j)
      bf[j] = *(const bf16x8*)&Bs[b][((wave * 4 + j) * 64 + lane) * 8];
    #pragma unroll
    for (int m = 0; m < 4; ++m) {
      int row = m * 16 + l16;
      f32x4 lo = *(const f32x4*)&As[b][row * 32 + (((quad * 2 + 0) ^ (l16 & 7)) * 4)];
      f32x4 hi = *(const f32x4*)&As[b][row * 32 + (((quad * 2 + 1) ^ (l16 & 7)) * 4)];
      bf16x8 af = cvt8(lo, hi);
      #pragma unroll
      for (int j = 0; j < 4; ++j)
        acc[m][j] = __builtin_amdgcn_mfma_f32_16x16x32_bf16(af, bf[j], acc[m][j], 0, 0, 0);
    }
    __builtin_amdgcn_sched_barrier(0);
    __builtin_amdgcn_s_barrier();          // all waves done reading buffer b
    __builtin_amdgcn_sched_barrier(0);
    if (ks < 14) STAGE(ks + 2, b);         // overwrite just-consumed buffer
    b ^= 1;
  }
  #undef STAGE

  // ---- epilogue: row = row0 + m*16 + quad*4 + rr, col = wave*64 + j*16 + l16
  #pragma unroll
  for (int m = 0; m < 4; ++m) {
    #pragma unroll
    for (int rr = 0; rr < 4; ++rr) {
      int row = row0 + m * 16 + quad * 4 + rr;
      if (row < M_NODES) {
        #pragma unroll
        for (int j = 0; j < 4; ++j) {
          H[(size_t)row * N_OUT + wave * 64 + j * 16 + l16] =
              f2bf_u(fast_tanh(acc[m][j][rr]));
        }
      }
    }
  }
}

// y[i,:] = sum_e vals[e]*x[col[e],:], x bf16 [M,256]. One wave/row; lane holds
// 4 features (8B/edge/lane -> full 512B row per edge, coalesced).
// 16-deep asm-volatile gather burst (R8: brought delivery to ~12.5 B/cy/CU,
// the per-CU fabric ceiling). Pad lanes clamp to the row's last col with
// v=0 (cache-hit, contribute nothing).
__global__ __launch_bounds__(256, 1) void spmm_bf_bf(
    const int* __restrict__ rp, const int* __restrict__ colv,
    const float* __restrict__ vals, const unsigned short* __restrict__ x,
    unsigned short* __restrict__ y) {
  int w = (blockIdx.x * 256 + threadIdx.x) >> 6;
  int lane = threadIdx.x & 63;
  int i = __builtin_amdgcn_readfirstlane(w);
  int s = rp[i], e = rp[i + 1];
  float a0 = 0.f, a1 = 0.f, a2 = 0.f, a3 = 0.f;
  const unsigned long long xb = (unsigned long long)(x) + (unsigned)(lane * 8);
  for (int k = s; k < e; k += 16) {
    int tl = min(k + lane, e - 1);
    int c_l = colv[tl];
    float v_l = (k + lane < e) ? vals[tl] : 0.f;
    unsigned long long pp[16];
    float vv[16];
    #pragma unroll
    for (int j = 0; j < 16; ++j) {
      int c = __shfl(c_l, j);
      vv[j] = __shfl(v_l, j);
      pp[j] = xb + ((unsigned long long)(unsigned)c << 9);
    }
    unsigned long long d[16];
    #pragma unroll
    for (int j = 0; j < 16; ++j)
      asm volatile("global_load_dwordx2 %0, %1, off" : "=v"(d[j]) : "v"(pp[j]));
    asm volatile("s_waitcnt vmcnt(0)" ::: "memory");
    __builtin_amdgcn_sched_barrier(0);
    #pragma unroll
    for (int j = 0; j < 16; ++j) {
      unsigned lo = (unsigned)d[j], hi = (unsigned)(d[j] >> 32);
      union { unsigned u; float f; } f0, f1, f2, f3;
      f0.u = lo << 16; f1.u = lo & 0xffff0000u;
      f2.u = hi << 16; f3.u = hi & 0xffff0000u;
      a0 += vv[j] * f0.f; a1 += vv[j] * f1.f;
      a2 += vv[j] * f2.f; a3 += vv[j] * f3.f;
    }
  }
  ushort4 o;
  o.x = f2bf_u(a0); o.y = f2bf_u(a1); o.z = f2bf_u(a2); o.w = f2bf_u(a3);
  *(ushort4*)(y + (size_t)i * N_OUT + lane * 4) = o;
}

// same but f32 output (final layer writes d_out)
__global__ __launch_bounds__(256, 1) void spmm_bf_f32(
    const int* __restrict__ rp, const int* __restrict__ colv,
    const float* __restrict__ vals, const unsigned short* __restrict__ x,
    float* __restrict__ y) {
  int w = (blockIdx.x * 256 + threadIdx.x) >> 6;
  int lane = threadIdx.x & 63;
  int i = __builtin_amdgcn_readfirstlane(w);
  int s = rp[i], e = rp[i + 1];
  float a0 = 0.f, a1 = 0.f, a2 = 0.f, a3 = 0.f;
  const unsigned long long xb = (unsigned long long)(x) + (unsigned)(lane * 8);
  for (int k = s; k < e; k += 16) {
    int tl = min(k + lane, e - 1);
    int c_l = colv[tl];
    float v_l = (k + lane < e) ? vals[tl] : 0.f;
    unsigned long long pp[16];
    float vv[16];
    #pragma unroll
    for (int j = 0; j < 16; ++j) {
      int c = __shfl(c_l, j);
      vv[j] = __shfl(v_l, j);
      pp[j] = xb + ((unsigned long long)(unsigned)c << 9);
    }
    unsigned long long d[16];
    #pragma unroll
    for (int j = 0; j < 16; ++j)
      asm volatile("global_load_dwordx2 %0, %1, off" : "=v"(d[j]) : "v"(pp[j]));
    asm volatile("s_waitcnt vmcnt(0)" ::: "memory");
    __builtin_amdgcn_sched_barrier(0);
    #pragma unroll
    for (int j = 0; j < 16; ++j) {
      unsigned lo = (unsigned)d[j], hi = (unsigned)(d[j] >> 32);
      union { unsigned u; float f; } f0, f1, f2, f3;
      f0.u = lo << 16; f1.u = lo & 0xffff0000u;
      f2.u = hi << 16; f3.u = hi & 0xffff0000u;
      a0 += vv[j] * f0.f; a1 += vv[j] * f1.f;
      a2 += vv[j] * f2.f; a3 += vv[j] * f3.f;
    }
  }
  float4 o = {a0, a1, a2, a3};
  *(float4*)(y + (size_t)i * N_OUT + lane * 4) = o;
}

extern "C" void kernel_launch(void* const* d_in, const int* in_sizes, int n_in,
                              void* d_out, int out_size, void* d_ws, size_t ws_size,
                              hipStream_t stream) {
  const float* features = (const float*)d_in[0];
  const float* weight   = (const float*)d_in[1];
  const int*   row      = (const int*)d_in[2];
  const int*   col      = (const int*)d_in[3];
  const float* vals     = (const float*)d_in[4];
  float* out = (float*)d_out;

  char* ws = (char*)d_ws;
  const size_t HB = (size_t)M_NODES * N_OUT * 2;   // 51,200,000 bf16 H
  const size_t RPB = 400016;                        // 100001 ints padded
  unsigned short* H  = (unsigned short*)ws;
  unsigned short* y1 = (unsigned short*)(ws + HB);
  int*   rp = (int*)(ws + 2 * HB);
  short* Wt = (short*)(ws + 2 * HB + RPB);
  // total need: 2*51.2MB + 400016 + 262144 = 103,062,160 B (fits)

  prep_w_kernel<<<64, 256, 0, stream>>>(weight, Wt);
  build_rp_kernel<<<(M_NODES + 1 + 255) / 256, 256, 0, stream>>>(row, rp);
  // 64 rows/block, 256 cols, 1563 blocks
  gemm_tanh_kernel<<<(M_NODES + 63) / 64, 256, 0, stream>>>(features, Wt, H);
  spmm_bf_bf<<<25000, 256, 0, stream>>>(rp, col, vals, H, y1);
  spmm_bf_f32<<<25000, 256, 0, stream>>>(rp, col, vals, y1, out);
}